// Round 18
// baseline (2785.941 us; speedup 1.0000x reference)
//
#include <hip/hip_runtime.h>
#include <math.h>

#define SS 2048
#define EE 1024
#define EPSD 1e-8
#define EPSF 1e-8f
#define NTH 256          // 4 waves, 1 per SIMD
#define NW  4
#define NG  32           // cosine groups
#define GS  64           // group size

#define DPP_XOR1 0xB1    // quad_perm [1,0,3,2]
#define DPP_XOR2 0x4E    // quad_perm [2,3,0,1]
#define DPP_HMIR 0x141   // row_half_mirror
#define DPP_MIR  0x140   // row_mirror

using f4 = float __attribute__((ext_vector_type(4)));
using f2 = float __attribute__((ext_vector_type(2)));
using i4 = int __attribute__((ext_vector_type(4)));

// LDS-only barrier (no vmcnt drain; x-traffic is within-thread-only).
__device__ __forceinline__ void bar_lds() {
  asm volatile("s_waitcnt lgkmcnt(0)" ::: "memory");
  __builtin_amdgcn_s_barrier();
  __builtin_amdgcn_sched_barrier(0);
}

// ---- f32 DPP primitives ----
template <int CTRL>
__device__ __forceinline__ float mov_dpp_f32(float v) {
  union { float f; int i; } a; a.f = v;
  const int n = __builtin_amdgcn_mov_dpp(a.i, CTRL, 0xF, 0xF, true);
  union { int i; float f; } r; r.i = n;
  return r.f;
}

template <int CTRL>
__device__ __forceinline__ float dpp_addf(float v) { return v + mov_dpp_f32<CTRL>(v); }

template <int CTRL>
__device__ __forceinline__ void amax_dppf(float& v, int& ix) {
  const float ov = mov_dpp_f32<CTRL>(v);
  const int oi = __builtin_amdgcn_mov_dpp(ix, CTRL, 0xF, 0xF, true);
  if (ov > v || (ov == v && oi < ix)) { v = ov; ix = oi; }
}

__device__ __forceinline__ void foldmaxf(float& v, int& ix, float ov, int oi) {
  if (ov > v || (ov == v && oi < ix)) { v = ov; ix = oi; }
}

// argmax fold carrying the candidate's post-merge links (pk) and next2 (n2)
__device__ __forceinline__ void foldmax4(float& v, int& ix, int& pk, int& n2,
                                         float ov, int oi, int opk, int on2) {
  if (ov > v || (ov == v && oi < ix)) { v = ov; ix = oi; pk = opk; n2 = on2; }
}

// f32 1/sqrt: v_rsq_f32 + 1 Newton.
__device__ __forceinline__ float rsqrt1f(float x) {
  float y = __builtin_amdgcn_rsqf(x);
  y = y * fmaf(-0.5f * x * y, y, 1.5f);
  return y;
}

// f32 1/x: v_rcp_f32 + 1 Newton.
__device__ __forceinline__ float rcp1f(float x) {
  float y = __builtin_amdgcn_rcpf(x);
  y = y * fmaf(-x, y, 2.0f);
  return y;
}

// f32 tanh for |z| <= ~1.2, rel err ~2e-7.
__device__ __forceinline__ float tanh_f32(float z) {
  const float u = 0.5f * z;
  const float s = u * u;
  float P = fmaf(s, -929569.0f / 638512875.0f, 21844.0f / 6081075.0f);
  P = fmaf(s, P, -1382.0f / 155925.0f);
  P = fmaf(s, P, 62.0f / 2835.0f);
  P = fmaf(s, P, -17.0f / 315.0f);
  P = fmaf(s, P, 2.0f / 15.0f);
  P = fmaf(s, P, -1.0f / 3.0f);
  const float t = fmaf(u * s, P, u);
  const float den = fmaf(t, t, 1.0f);
  return (2.0f * t) * rcp1f(den);
}

__device__ __forceinline__ double wave_sum64(double v) {
#pragma unroll
  for (int off = 32; off > 0; off >>= 1) v += __shfl_down(v, off, 64);
  return v;
}

__global__ void banyan_init(const int* __restrict__ seqs, const float* __restrict__ emb,
                            float* __restrict__ x, double* __restrict__ norms) {
  __shared__ double sh[4];
  const int s = blockIdx.x;
  const int row = seqs[s];
  double acc = 0.0;
  for (int e = threadIdx.x; e < EE; e += 256) {
    const float v = emb[(size_t)row * EE + e];
    x[(size_t)s * EE + e] = v;
    acc += (double)v * (double)v;
  }
  acc = wave_sum64(acc);
  const int lane = threadIdx.x & 63;
  const int w = threadIdx.x >> 6;
  if (lane == 0) sh[w] = acc;
  __syncthreads();
  if (threadIdx.x == 0) norms[s] = sqrt(sh[0] + sh[1] + sh[2] + sh[3]);
}

__global__ void banyan_dots(const float* __restrict__ x, double* __restrict__ num) {
  __shared__ double sh[4];
  const int s = blockIdx.x;
  double acc = 0.0;
  for (int e = threadIdx.x; e < EE; e += 256) {
    acc += (double)x[(size_t)s * EE + e] * (double)x[(size_t)(s + 1) * EE + e];
  }
  acc = wave_sum64(acc);
  const int lane = threadIdx.x & 63;
  const int w = threadIdx.x >> 6;
  if (lane == 0) sh[w] = acc;
  __syncthreads();
  if (threadIdx.x == 0) num[s] = sh[0] + sh[1] + sh[2] + sh[3];
}

// Selection-before-barrier structure: the next quad is computed post-B from
// {S-scan, U-scans, cosP, cosJ} (each candidate carrying post-merge links),
// so each region issues all 4 row loads IMMEDIATELY after bar C.
__global__ __launch_bounds__(NTH, 1) void banyan_main(
    float* __restrict__ x, const double* __restrict__ norms_in, const double* __restrict__ num_in,
    const float* __restrict__ Wl, const float* __restrict__ Wr, const float* __restrict__ Bb,
    float* __restrict__ out) {
  __shared__ float cosL[SS];
  __shared__ float rcpN[SS];       // 1 / max(norm, eps)
  __shared__ unsigned listL[SS];   // next lo16, prev hi16 (0xFFFF = -1)
  __shared__ int next2L[SS];       // next[next[s]] (-1 = none)
  __shared__ __align__(8) f2 gRec[NG];        // {max, bitcast(idx)} per group
  __shared__ float r3v[3][16];                // [sum][row-slot]
  __shared__ __align__(16) int r4s[3][4];     // U-winner {val,idx,links,next2} per scan wave
  __shared__ __align__(16) int r5s[4];        // S-winner {val,idx,links,next2}

  const int t = threadIdx.x;
  const int lane = t & 63;
  const int w = t >> 6;
  const int m16 = lane & 15;
  const float NEGINF = -__builtin_inff();

  for (int s = t; s < SS; s += NTH) {
    rcpN[s] = (float)(1.0 / fmax(norms_in[s], EPSD));
    const int nx = (s + 1 < SS) ? (s + 1) : -1;
    const int pv = s - 1;
    listL[s] = ((unsigned)nx & 0xFFFFu) | (((unsigned)pv & 0xFFFFu) << 16);
    next2L[s] = (s + 2 < SS) ? (s + 2) : -1;
  }
  __syncthreads();
  for (int s = t; s < SS; s += NTH) {
    cosL[s] = (s < SS - 1)
                  ? (float)((num_in[s] * (double)rcpN[s]) * (double)rcpN[s + 1])
                  : NEGINF;
  }
  __syncthreads();
  for (int m = 0; m < NG / NW; ++m) {
    const int g = w * (NG / NW) + m;
    float v = cosL[g * GS + lane];
    int ix = g * GS + lane;
#pragma unroll
    for (int off = 32; off > 0; off >>= 1) {
      const float ov = __shfl_down(v, off, 64);
      const int oi = __shfl_down(ix, off, 64);
      if (ov > v || (ov == v && oi < ix)) { v = ov; ix = oi; }
    }
    if (lane == 0) { f2 r; r.x = v; r.y = __int_as_float(ix); gRec[g] = r; }
  }
  __syncthreads();

  // Thread t owns elements {4t..4t+3}.
  const int e0 = 4 * t;
  const f4 wl = *(const f4*)&Wl[e0];
  const f4 wr = *(const f4*)&Wr[e0];
  const f4 bv = *(const f4*)&Bb[e0];
  int head = 0;

  // ---- prologue: initial argmax + link reads -> quad 0 ----
  int i, j, p, nj, p2, n2, j2;
  {
    const f2 rA = gRec[m16];
    const f2 rB = gRec[m16 + 16];
    float v = rA.x;
    int ix = __float_as_int(rA.y);
    foldmaxf(v, ix, rB.x, __float_as_int(rB.y));
    amax_dppf<DPP_XOR1>(v, ix);
    amax_dppf<DPP_XOR2>(v, ix);
    amax_dppf<DPP_HMIR>(v, ix);
    amax_dppf<DPP_MIR>(v, ix);
    i = __builtin_amdgcn_readfirstlane(ix);
    const unsigned pki = listL[i];
    j = (int)(short)(pki & 0xFFFFu);
    p = (int)(short)(pki >> 16);
    nj = next2L[i];
    p2 = (p >= 0) ? p : i;
    n2 = (nj >= 0) ? nj : i;
    j2 = (j >= 0) ? j : i;
  }

  for (int step = 0; step < SS - 1; ++step) {
    if (p < 0) head = j;
    // ---- region start: issue ALL FOUR row loads (zero front-end) ----
    const f4 xi = *(const f4*)&x[(size_t)i * EE + e0];
    const f4 xj = *(const f4*)&x[(size_t)j2 * EE + e0];
    const f4 xp = *(const f4*)&x[(size_t)p2 * EE + e0];
    const f4 xn = *(const f4*)&x[(size_t)n2 * EE + e0];

    const int gi_ = i >> 6;
    const int gp_ = (p >= 0) ? (p >> 6) : gi_;
    const int gj_ = j >> 6;
    const int grp = (w == 0) ? gi_ : (w == 1) ? gp_ : gj_;
    const int base = grp * GS + m16;

    // ---- phase A (under the load window) ----
    const float rcpP = rcpN[p2];
    const float rcpNN = rcpN[n2];
    const unsigned lpp = listL[p2];
    const int pp = (p >= 0) ? (int)(short)(lpp >> 16) : -1;
    const int n2J = next2L[j2];

    float stv = NEGINF; int sti = 0;
    if (w < 3) {
      // stable scan of this wave's touched group (i/p/j masked)
      float cc0 = cosL[base];
      float cc1 = cosL[base + 16];
      float cc2 = cosL[base + 32];
      float cc3 = cosL[base + 48];
      const int pos0 = base, pos1 = base + 16, pos2 = base + 32, pos3 = base + 48;
      if (pos0 == i || pos0 == p || pos0 == j) cc0 = NEGINF;
      if (pos1 == i || pos1 == p || pos1 == j) cc1 = NEGINF;
      if (pos2 == i || pos2 == p || pos2 == j) cc2 = NEGINF;
      if (pos3 == i || pos3 == p || pos3 == j) cc3 = NEGINF;
      float cv = cc0; int gx = pos0;
      foldmaxf(cv, gx, cc1, pos1);
      foldmaxf(cv, gx, cc2, pos2);
      foldmaxf(cv, gx, cc3, pos3);
      amax_dppf<DPP_XOR1>(cv, gx);
      amax_dppf<DPP_XOR2>(cv, gx);
      amax_dppf<DPP_HMIR>(cv, gx);
      amax_dppf<DPP_MIR>(cv, gx);
      stv = cv; sti = gx;
      // pre-read winner's links (stable slots: winner != i,p,j by masking)
      const int gxm = __builtin_amdgcn_readfirstlane(gx) & (SS - 1);
      const unsigned lkU = listL[gxm];
      const int n2U = next2L[gxm];
      if (lane == 0) {
        r4s[w][0] = __float_as_int(cv); r4s[w][1] = gx;
        r4s[w][2] = (int)lkU; r4s[w][3] = n2U;
      }
    } else {
      // S-scan over untouched groups (touched groups wholly masked)
      const f2 rA = gRec[m16];
      const f2 rB = gRec[m16 + 16];
      const bool mA = (m16 == gi_) | (m16 == gp_) | (m16 == gj_);
      const int gB = m16 + 16;
      const bool mB = (gB == gi_) | (gB == gp_) | (gB == gj_);
      float sv = mA ? NEGINF : rA.x;
      int si = __float_as_int(rA.y);
      foldmaxf(sv, si, mB ? NEGINF : rB.x, __float_as_int(rB.y));
      amax_dppf<DPP_XOR1>(sv, si);
      amax_dppf<DPP_XOR2>(sv, si);
      amax_dppf<DPP_HMIR>(sv, si);
      amax_dppf<DPP_MIR>(sv, si);
      const int siU = __builtin_amdgcn_readfirstlane(si) & (SS - 1);
      const unsigned lkS = listL[siU];
      const int n2S = next2L[siU];
      if (lane == 0) {
        r5s[0] = __float_as_int(sv); r5s[1] = si;
        r5s[2] = (int)lkS; r5s[3] = n2S;
      }
    }

    // ---- consume loads: tanh + fused 3-sum + DPP row reduce ----
    const float q0 = tanh_f32(fmaf(xi.x, wl.x, fmaf(xj.x, wr.x, bv.x)));
    const float q1 = tanh_f32(fmaf(xi.y, wl.y, fmaf(xj.y, wr.y, bv.y)));
    const float q2 = tanh_f32(fmaf(xi.z, wl.z, fmaf(xj.z, wr.z, bv.z)));
    const float q3 = tanh_f32(fmaf(xi.w, wl.w, fmaf(xj.w, wr.w, bv.w)));

    float s0 = fmaf(q0, q0, fmaf(q1, q1, fmaf(q2, q2, q3 * q3)));
    float s1 = fmaf(xp.x, q0, fmaf(xp.y, q1, fmaf(xp.z, q2, xp.w * q3)));
    float s2 = fmaf(q0, xn.x, fmaf(q1, xn.y, fmaf(q2, xn.z, q3 * xn.w)));
    s1 = (p >= 0) ? s1 : 0.0f;
    s2 = (nj >= 0) ? s2 : 0.0f;
    s0 = dpp_addf<DPP_XOR1>(s0); s1 = dpp_addf<DPP_XOR1>(s1); s2 = dpp_addf<DPP_XOR1>(s2);
    s0 = dpp_addf<DPP_XOR2>(s0); s1 = dpp_addf<DPP_XOR2>(s1); s2 = dpp_addf<DPP_XOR2>(s2);
    s0 = dpp_addf<DPP_HMIR>(s0); s1 = dpp_addf<DPP_HMIR>(s1); s2 = dpp_addf<DPP_HMIR>(s2);
    s0 = dpp_addf<DPP_MIR>(s0);  s1 = dpp_addf<DPP_MIR>(s1);  s2 = dpp_addf<DPP_MIR>(s2);
    if (m16 == 0) {
      const int slot = w * 4 + (lane >> 4);
      r3v[0][slot] = s0; r3v[1][slot] = s1; r3v[2][slot] = s2;
    }
    bar_lds();  // B

    // ---- post-B: parallel LDS reads, fold, cosines, SELECT, writes ----
    {
      f4 st; st.x = q0; st.y = q1; st.z = q2; st.w = q3;
      *(f4*)&x[(size_t)j * EE + e0] = st;   // parent store under compute
    }
    float t0 = r3v[0][m16];
    float t1 = r3v[1][m16];
    float t2 = r3v[2][m16];
    const i4 R0 = *(const i4*)&r4s[0][0];
    const i4 R1 = *(const i4*)&r4s[1][0];
    const i4 R2 = *(const i4*)&r4s[2][0];
    const i4 R5 = *(const i4*)&r5s[0];
    t0 = dpp_addf<DPP_XOR1>(t0); t1 = dpp_addf<DPP_XOR1>(t1); t2 = dpp_addf<DPP_XOR1>(t2);
    t0 = dpp_addf<DPP_XOR2>(t0); t1 = dpp_addf<DPP_XOR2>(t1); t2 = dpp_addf<DPP_XOR2>(t2);
    t0 = dpp_addf<DPP_HMIR>(t0); t1 = dpp_addf<DPP_HMIR>(t1); t2 = dpp_addf<DPP_HMIR>(t2);
    t0 = dpp_addf<DPP_MIR>(t0);  t1 = dpp_addf<DPP_MIR>(t1);  t2 = dpp_addf<DPP_MIR>(t2);
    const float invnn = (t0 > EPSF * EPSF) ? rsqrt1f(t0) : 1e8f;
    const float cosP = (p >= 0) ? (t1 * rcpP) * invnn : NEGINF;
    const float cosJnew = (nj >= 0) ? (t2 * rcpNN) * invnn : NEGINF;

    // 6-way select with links (uniform across all lanes/waves)
    float bvv = __int_as_float(R5.x); int bii = R5.y; int bpk = R5.z; int bn2 = R5.w;
    foldmax4(bvv, bii, bpk, bn2, __int_as_float(R0.x), R0.y, R0.z, R0.w);
    foldmax4(bvv, bii, bpk, bn2, __int_as_float(R1.x), R1.y, R1.z, R1.w);
    foldmax4(bvv, bii, bpk, bn2, __int_as_float(R2.x), R2.y, R2.z, R2.w);
    foldmax4(bvv, bii, bpk, bn2, cosP, p,
             (int)(((unsigned)j & 0xFFFFu) | (((unsigned)pp & 0xFFFFu) << 16)), nj);
    foldmax4(bvv, bii, bpk, bn2, cosJnew, j,
             (int)(((unsigned)nj & 0xFFFFu) | (((unsigned)p & 0xFFFFu) << 16)), n2J);
    if (bii != p && bii != j && bii == pp) bn2 = j;  // next2 staleness fix
    const int iN = __builtin_amdgcn_readfirstlane(bii);
    const unsigned bpkU = (unsigned)__builtin_amdgcn_readfirstlane(bpk);
    const int njN = __builtin_amdgcn_readfirstlane(bn2);
    const int jN = (int)(short)(bpkU & 0xFFFFu);
    const int pN = (int)(short)(bpkU >> 16);

    // gRec repair (w<3) and scalar state writes (w3) for THIS merge
    if (w < 3) {
      float cv = stv; int gx = sti;
      if (p >= 0 && gp_ == grp) foldmaxf(cv, gx, cosP, p);
      if (gj_ == grp) foldmaxf(cv, gx, cosJnew, j);
      if (lane == 0) {
        f2 r; r.x = cv; r.y = __int_as_float(gx);
        gRec[grp] = r;
      }
    } else if (lane == 0) {
      cosL[i] = NEGINF;
      cosL[j] = cosJnew;
      rcpN[j] = invnn;
      listL[j] = ((unsigned)nj & 0xFFFFu) | (((unsigned)p & 0xFFFFu) << 16);
      if (p >= 0) {
        cosL[p] = cosP;
        listL[p] = (lpp & 0xFFFF0000u) | ((unsigned)j & 0xFFFFu);
        next2L[p] = nj;
        if (pp >= 0) next2L[pp] = j;
      }
    }
    bar_lds();  // C
    // commit next quad
    i = iN; j = jN; p = pN; nj = njN;
    p2 = (p >= 0) ? p : i;
    n2 = (nj >= 0) ? nj : i;
    j2 = (j >= 0) ? j : i;
  }

  {
    const f4 h = *(const f4*)&x[(size_t)head * EE + e0];
    *(f4*)&out[e0] = h;
  }
}

extern "C" void kernel_launch(void* const* d_in, const int* in_sizes, int n_in,
                              void* d_out, int out_size, void* d_ws, size_t ws_size,
                              hipStream_t stream) {
  const int* seqs = (const int*)d_in[0];
  const float* emb = (const float*)d_in[1];
  const float* Wl = (const float*)d_in[2];
  const float* Wr = (const float*)d_in[3];
  const float* Bb = (const float*)d_in[4];
  float* out = (float*)d_out;

  const size_t xbytesF = (size_t)SS * EE * sizeof(float);
  float* x = (float*)d_ws;
  double* norms = (double*)((char*)d_ws + xbytesF);
  double* num = norms + SS;
  hipLaunchKernelGGL(banyan_init, dim3(SS), dim3(256), 0, stream, seqs, emb, x, norms);
  hipLaunchKernelGGL(banyan_dots, dim3(SS - 1), dim3(256), 0, stream, x, num);
  hipLaunchKernelGGL(banyan_main, dim3(1), dim3(NTH), 0, stream,
                     x, norms, num, Wl, Wr, Bb, out);
}